// Round 3
// baseline (207.259 us; speedup 1.0000x reference)
//
#include <hip/hip_runtime.h>

// irreps: x1 = 128x0e + 128x1o (512), x2 = 1x0e + 1x1o (4), w = 5*128 (640)
// out = 128x0e + 128x1o (512). All fp32. Memory-bound streaming op.
//
// Per edge z, channel u:
//   s = x1[z,u]; v = x1[z,128+3u .. +3); a = x2[z,0]; b = x2[z,1..4)
//   out[z,u]        = s*a*w0[u] + (1/sqrt3)*(v.b)*w3[u]
//   out[z,128+3u+k] = (1/sqrt3)*s*w1[u]*b[k] + (1/sqrt3)*a*w2[u]*v[k]
//                   + (1/sqrt6)*w4[u]*(v x b)[k]
//
// Mapping: 32 threads per edge, each owns 4 channels (all accesses aligned
// 16B). Each thread processes TWO consecutive edges with all 20 loads issued
// before any use -> ~2x memory-level parallelism per wave vs R1 (which was
// register-starved at VGPR=36 and serialized its loads).
//
// Native clang vectors (ext_vector_type) are used instead of HIP float4 so
// __builtin_nontemporal_store accepts them.

typedef float f32x4 __attribute__((ext_vector_type(4)));

__global__ __launch_bounds__(256, 4) void tp_uvu_kernel(
    const float* __restrict__ x1,
    const float* __restrict__ x2,
    const float* __restrict__ w,
    float* __restrict__ out,
    int n_edges)
{
    const int tid  = blockIdx.x * blockDim.x + threadIdx.x;
    const int pair = tid >> 5;         // pair of edges
    const int g    = tid & 31;         // channel group: channels 4g..4g+3
    const int z0   = pair * 2;
    if (z0 >= n_edges) return;
    const int ne = (z0 + 1 < n_edges) ? 2 : 1;

    constexpr float inv_sqrt3 = 0.57735026918962576f;
    constexpr float inv_sqrt6 = 0.40824829046386302f;

    f32x4 x2v[2], s4[2], va[2], vb[2], vc[2], w0[2], w1[2], w2[2], w3[2], w4[2];

    // ---- load phase: issue everything before any consumption ----
#pragma unroll
    for (int e = 0; e < 2; ++e) {
        if (e >= ne) break;
        const int z = z0 + e;
        const float* x1row = x1 + (size_t)z * 512;
        const float* wrow  = w  + (size_t)z * 640;
        x2v[e] = *reinterpret_cast<const f32x4*>(x2 + (size_t)z * 4);
        s4[e]  = *reinterpret_cast<const f32x4*>(x1row + 4 * g);
        va[e]  = *reinterpret_cast<const f32x4*>(x1row + 128 + 12 * g);
        vb[e]  = *reinterpret_cast<const f32x4*>(x1row + 128 + 12 * g + 4);
        vc[e]  = *reinterpret_cast<const f32x4*>(x1row + 128 + 12 * g + 8);
        w0[e]  = *reinterpret_cast<const f32x4*>(wrow +   0 + 4 * g);
        w1[e]  = *reinterpret_cast<const f32x4*>(wrow + 128 + 4 * g);
        w2[e]  = *reinterpret_cast<const f32x4*>(wrow + 256 + 4 * g);
        w3[e]  = *reinterpret_cast<const f32x4*>(wrow + 384 + 4 * g);
        w4[e]  = *reinterpret_cast<const f32x4*>(wrow + 512 + 4 * g);
    }

    // ---- compute + store phase ----
#pragma unroll
    for (int e = 0; e < 2; ++e) {
        if (e >= ne) break;
        const int z = z0 + e;
        float* outrow = out + (size_t)z * 512;

        const float a  = x2v[e].x;
        const float bx = x2v[e].y, by = x2v[e].z, bz = x2v[e].w;

        const float s[4]   = {s4[e].x, s4[e].y, s4[e].z, s4[e].w};
        const float vv[12] = {va[e].x, va[e].y, va[e].z, va[e].w,
                              vb[e].x, vb[e].y, vb[e].z, vb[e].w,
                              vc[e].x, vc[e].y, vc[e].z, vc[e].w};
        const float W0[4]  = {w0[e].x, w0[e].y, w0[e].z, w0[e].w};
        const float W1[4]  = {w1[e].x, w1[e].y, w1[e].z, w1[e].w};
        const float W2[4]  = {w2[e].x, w2[e].y, w2[e].z, w2[e].w};
        const float W3[4]  = {w3[e].x, w3[e].y, w3[e].z, w3[e].w};
        const float W4[4]  = {w4[e].x, w4[e].y, w4[e].z, w4[e].w};

        float os[4];
        float ov[12];
#pragma unroll
        for (int c = 0; c < 4; ++c) {
            const float vx = vv[3 * c + 0];
            const float vy = vv[3 * c + 1];
            const float vz = vv[3 * c + 2];
            const float dot = vx * bx + vy * by + vz * bz;
            os[c] = s[c] * a * W0[c] + inv_sqrt3 * dot * W3[c];

            // v x b
            const float cx = vy * bz - vz * by;
            const float cy = vz * bx - vx * bz;
            const float cz = vx * by - vy * bx;

            const float t1 = inv_sqrt3 * s[c] * W1[c];
            const float t2 = inv_sqrt3 * a   * W2[c];
            const float t4 = inv_sqrt6 * W4[c];
            ov[3 * c + 0] = t1 * bx + t2 * vx + t4 * cx;
            ov[3 * c + 1] = t1 * by + t2 * vy + t4 * cy;
            ov[3 * c + 2] = t1 * bz + t2 * vz + t4 * cz;
        }

        // non-temporal stores: output is write-once, never re-read; keep L2/L3
        // capacity for the input streams.
        f32x4 o0 = {os[0], os[1], os[2], os[3]};
        f32x4 o1 = {ov[0], ov[1], ov[2], ov[3]};
        f32x4 o2 = {ov[4], ov[5], ov[6], ov[7]};
        f32x4 o3 = {ov[8], ov[9], ov[10], ov[11]};
        __builtin_nontemporal_store(o0, reinterpret_cast<f32x4*>(outrow + 4 * g));
        __builtin_nontemporal_store(o1, reinterpret_cast<f32x4*>(outrow + 128 + 12 * g));
        __builtin_nontemporal_store(o2, reinterpret_cast<f32x4*>(outrow + 128 + 12 * g + 4));
        __builtin_nontemporal_store(o3, reinterpret_cast<f32x4*>(outrow + 128 + 12 * g + 8));
    }
}

extern "C" void kernel_launch(void* const* d_in, const int* in_sizes, int n_in,
                              void* d_out, int out_size, void* d_ws, size_t ws_size,
                              hipStream_t stream) {
    const float* x1 = (const float*)d_in[0];
    const float* x2 = (const float*)d_in[1];
    const float* w  = (const float*)d_in[2];
    float* out = (float*)d_out;

    const int n_edges = in_sizes[0] / 512;
    const int n_pairs = (n_edges + 1) / 2;
    const long long total_threads = (long long)n_pairs * 32;
    const int block = 256;
    const int grid = (int)((total_threads + block - 1) / block);

    tp_uvu_kernel<<<grid, block, 0, stream>>>(x1, x2, w, out, n_edges);
}

// Round 4
// 156.580 us; speedup vs baseline: 1.3237x; 1.3237x over previous
//
#include <hip/hip_runtime.h>

// irreps: x1 = 128x0e + 128x1o (512), x2 = 1x0e + 1x1o (4), w = 5*128 (640)
// out = 128x0e + 128x1o (512). All fp32. Memory-bound streaming op.
//
// Per edge z, channel u:
//   s = x1[z,u]; v = x1[z,128+3u .. +3); a = x2[z,0]; b = x2[z,1..4)
//   out[z,u]        = s*a*w0[u] + (1/sqrt3)*(v.b)*w3[u]
//   out[z,128+3u+k] = (1/sqrt3)*s*w1[u]*b[k] + (1/sqrt3)*a*w2[u]*v[k]
//                   + (1/sqrt6)*w4[u]*(v x b)[k]
//
// Mapping: 32 threads per edge, each owns 4 channels; every global access is
// an aligned 16B dwordx4. One edge-slice per thread (R1 structure — VGPR
// stays <=64 so occupancy stays at 8 waves/SIMD).
//
// R3 lesson: batching 2 edges + launch_bounds(256,4) + nt-stores LOST
// occupancy (72->40%) and BW scaled down with it. Here instead we keep
// occupancy and fix per-wave load serialization: sched_barrier(0) pins all
// 10 loads to issue back-to-back BEFORE the compute phase (R1's VGPR=36
// proves the compiler was sinking loads into the consume phase, leaving only
// ~3 in flight).

typedef float f32x4 __attribute__((ext_vector_type(4)));

__global__ __launch_bounds__(256) void tp_uvu_kernel(
    const float* __restrict__ x1,
    const float* __restrict__ x2,
    const float* __restrict__ w,
    float* __restrict__ out,
    int n_edges)
{
    const int tid = blockIdx.x * blockDim.x + threadIdx.x;
    const int z = tid >> 5;        // edge index
    const int g = tid & 31;        // channel group: channels 4g..4g+3
    if (z >= n_edges) return;

    constexpr float inv_sqrt3 = 0.57735026918962576f;
    constexpr float inv_sqrt6 = 0.40824829046386302f;

    const float* x1row  = x1  + (size_t)z * 512;
    const float* wrow   = w   + (size_t)z * 640;
    float*       outrow = out + (size_t)z * 512;

    // ---- load phase: all 10 loads issued before any consumption ----
    const f32x4 x2v = *reinterpret_cast<const f32x4*>(x2 + (size_t)z * 4);
    const f32x4 s4  = *reinterpret_cast<const f32x4*>(x1row + 4 * g);
    const f32x4 va  = *reinterpret_cast<const f32x4*>(x1row + 128 + 12 * g);
    const f32x4 vb  = *reinterpret_cast<const f32x4*>(x1row + 128 + 12 * g + 4);
    const f32x4 vc  = *reinterpret_cast<const f32x4*>(x1row + 128 + 12 * g + 8);
    const f32x4 w0  = *reinterpret_cast<const f32x4*>(wrow +   0 + 4 * g);
    const f32x4 w1  = *reinterpret_cast<const f32x4*>(wrow + 128 + 4 * g);
    const f32x4 w2  = *reinterpret_cast<const f32x4*>(wrow + 256 + 4 * g);
    const f32x4 w3  = *reinterpret_cast<const f32x4*>(wrow + 384 + 4 * g);
    const f32x4 w4  = *reinterpret_cast<const f32x4*>(wrow + 512 + 4 * g);

    // Scheduling fence: nothing crosses. Forces all loads above to be issued
    // before the compute below is scheduled (prevents load sinking / register
    // reuse that serializes the memory pipeline).
    __builtin_amdgcn_sched_barrier(0);

    // ---- compute + store phase ----
    const float a  = x2v.x;
    const float bx = x2v.y, by = x2v.z, bz = x2v.w;

    const float s[4]   = {s4.x, s4.y, s4.z, s4.w};
    const float vv[12] = {va.x, va.y, va.z, va.w,
                          vb.x, vb.y, vb.z, vb.w,
                          vc.x, vc.y, vc.z, vc.w};
    const float W0[4]  = {w0.x, w0.y, w0.z, w0.w};
    const float W1[4]  = {w1.x, w1.y, w1.z, w1.w};
    const float W2[4]  = {w2.x, w2.y, w2.z, w2.w};
    const float W3[4]  = {w3.x, w3.y, w3.z, w3.w};
    const float W4[4]  = {w4.x, w4.y, w4.z, w4.w};

    float os[4];
    float ov[12];
#pragma unroll
    for (int c = 0; c < 4; ++c) {
        const float vx = vv[3 * c + 0];
        const float vy = vv[3 * c + 1];
        const float vz = vv[3 * c + 2];
        const float dot = vx * bx + vy * by + vz * bz;
        os[c] = s[c] * a * W0[c] + inv_sqrt3 * dot * W3[c];

        // v x b
        const float cx = vy * bz - vz * by;
        const float cy = vz * bx - vx * bz;
        const float cz = vx * by - vy * bx;

        const float t1 = inv_sqrt3 * s[c] * W1[c];
        const float t2 = inv_sqrt3 * a   * W2[c];
        const float t4 = inv_sqrt6 * W4[c];
        ov[3 * c + 0] = t1 * bx + t2 * vx + t4 * cx;
        ov[3 * c + 1] = t1 * by + t2 * vy + t4 * cy;
        ov[3 * c + 2] = t1 * bz + t2 * vz + t4 * cz;
    }

    f32x4 o0 = {os[0], os[1], os[2], os[3]};
    f32x4 o1 = {ov[0], ov[1], ov[2], ov[3]};
    f32x4 o2 = {ov[4], ov[5], ov[6], ov[7]};
    f32x4 o3 = {ov[8], ov[9], ov[10], ov[11]};
    *reinterpret_cast<f32x4*>(outrow + 4 * g)            = o0;
    *reinterpret_cast<f32x4*>(outrow + 128 + 12 * g)     = o1;
    *reinterpret_cast<f32x4*>(outrow + 128 + 12 * g + 4) = o2;
    *reinterpret_cast<f32x4*>(outrow + 128 + 12 * g + 8) = o3;
}

extern "C" void kernel_launch(void* const* d_in, const int* in_sizes, int n_in,
                              void* d_out, int out_size, void* d_ws, size_t ws_size,
                              hipStream_t stream) {
    const float* x1 = (const float*)d_in[0];
    const float* x2 = (const float*)d_in[1];
    const float* w  = (const float*)d_in[2];
    float* out = (float*)d_out;

    const int n_edges = in_sizes[0] / 512;
    const long long total_threads = (long long)n_edges * 32;
    const int block = 256;
    const int grid = (int)((total_threads + block - 1) / block);

    tp_uvu_kernel<<<grid, block, 0, stream>>>(x1, x2, w, out, n_edges);
}